// Round 4
// baseline (809.264 us; speedup 1.0000x reference)
//
#include <hip/hip_runtime.h>
#include <stdint.h>

#define K_CODES 1024
#define DDIM 64
#define BM 128            // rows per block
#define HW 4096           // 64*64
#define CHW 262144        // 64*64*64

// output offsets (float32 elements, concat in reference return order)
#define OFF_Q    0ull
#define OFF_LOSS 4194304ull
#define OFF_PERP 4194305ull
#define OFF_ENC  4194306ull
#define OFF_IND  71303170ull
#define OFF_DIST 71368706ull

// workspace layout (bytes)
#define WS_E2   0
#define WS_HIST 4096
#define WS_SSD  8192

__global__ void vq_init(const float* __restrict__ emb, float* __restrict__ e2w,
                        unsigned* __restrict__ hist, double* __restrict__ ssd) {
    int k = blockIdx.x * 256 + threadIdx.x;
    if (k < K_CODES) {
        const float* row = emb + (size_t)k * DDIM;
        float s = 0.f;
        #pragma unroll
        for (int d = 0; d < DDIM; ++d) s = fmaf(row[d], row[d], s);
        e2w[k] = s;
        hist[k] = 0u;
    }
    if (k == 0) *ssd = 0.0;
}

// Block: 256 threads, handles BM=128 consecutive flattened rows (two (b,h) pairs)
// against all 1024 codes. Thread tile: 8 rows x 8 codes.
// tid -> kg = tid&7 (code group), mg = (tid>>3)&15 (row group), slab = tid>>7.
//
// NUMERICS: the np reference computes distances in fp32 as
//   d = fl( fl(z2 + e2_k) - fl(2*z.e_k) )   (values ~64 -> quantized to ulp 7.6e-6)
// and argmin picks the LOWEST index among quantized ties. We replicate that
// rounding chain exactly (t1 = z2+e2 rounded add; fmaf(-2,acc,t1) single-rounds
// t1 - 2*dot, identical to np since fl(2*dot)=2*dot). Sub-ulp differences in
// z2 shift all k uniformly (same-binade grid shift -> comparisons invariant);
// sub-ulp dot/e2 differences flip comparisons with probability ~1e-4 per tie row.
__global__ __launch_bounds__(256, 2) void vq_main(
    const float* __restrict__ lat, const float* __restrict__ emb,
    const float* __restrict__ e2w, unsigned* __restrict__ hist,
    double* __restrict__ ssd, float* __restrict__ out)
{
    // z rows stride 68 + extra 4 words per 8-row group -> conflict-free b128 broadcast reads
    __shared__ float z_s[BM * 68 + (BM / 8) * 4];     // 8768 floats
    __shared__ float e_s[128 * 68];                   // 8704 floats (reused for argmin reduce)
    __shared__ float z2_s[BM];                        // reused as fidx after kt loop
    __shared__ float e2_s[128];
    __shared__ float red_s[4];

    const int tid  = threadIdx.x;
    const int kg   = tid & 7;
    const int mg   = (tid >> 3) & 15;
    const int slab = tid >> 7;
    const int n0   = blockIdx.x * BM;

    // ---- stage z tile (global NCHW -> LDS row-major [r][d]) ----
    {
        const int w    = tid & 63;
        const int p    = (tid >> 6) & 1;
        const int half = tid >> 7;
        const int r    = p * 64 + w;
        const int n    = n0 + r;
        const int b    = n >> 12;
        const int h    = (n >> 6) & 63;
        const float* src = lat + (size_t)b * CHW + (size_t)h * 64 + w;
        float* dst = z_s + r * 68 + (r >> 3) * 4;
        #pragma unroll
        for (int dd = 0; dd < 32; ++dd) {
            int d = half * 32 + dd;
            dst[d] = src[(size_t)d * HW];
        }
    }
    __syncthreads();
    if (tid < BM) {
        const float* zr = z_s + tid * 68 + (tid >> 3) * 4;
        float s = 0.f;
        #pragma unroll
        for (int d = 0; d < DDIM; ++d) s = fmaf(zr[d], zr[d], s);
        z2_s[tid] = s;
    }
    // z2_s visibility covered by the sync inside the k-tile loop below

    const int kbl = slab * 64 + kg * 8;   // local code base within 128-code tile
    float min1[8];
    int   idx1[8];
    #pragma unroll
    for (int i = 0; i < 8; ++i) { min1[i] = 3.4e38f; idx1[i] = 0; }

    float* dist_out = out + OFF_DIST;
    float* enc_out  = out + OFF_ENC;

    const float* zbase = z_s + (mg * 8) * 68 + mg * 4;
    const float* ebase = e_s + kbl * 68;

    for (int kt = 0; kt < 8; ++kt) {
        __syncthreads();   // previous tile's e_s reads done
        // ---- stage e tile: 128 codes x 64 dims, XOR-swizzled d4 blocks ----
        {
            const int d4 = tid & 15;
            const int kr = tid >> 4;   // 0..15
            #pragma unroll
            for (int jj = 0; jj < 8; ++jj) {
                int kl = kr + 16 * jj;
                const float4 ev = *(const float4*)(emb + (size_t)(kt * 128 + kl) * DDIM + d4 * 4);
                *(float4*)(e_s + kl * 68 + ((d4 ^ ((kl >> 3) & 7)) << 2)) = ev;
            }
            if (tid < 128) e2_s[tid] = e2w[kt * 128 + tid];
        }
        __syncthreads();

        float acc[8][8];
        #pragma unroll
        for (int i = 0; i < 8; ++i)
            #pragma unroll
            for (int j = 0; j < 8; ++j) acc[i][j] = 0.f;

        #pragma unroll 2
        for (int d4 = 0; d4 < 16; ++d4) {
            float4 zf[8], ef[8];
            #pragma unroll
            for (int i = 0; i < 8; ++i)
                zf[i] = *(const float4*)(zbase + i * 68 + (d4 << 2));
            #pragma unroll
            for (int j = 0; j < 8; ++j)
                ef[j] = *(const float4*)(ebase + j * 68 + ((d4 ^ kg) << 2));
            #pragma unroll
            for (int i = 0; i < 8; ++i)
                #pragma unroll
                for (int j = 0; j < 8; ++j) {
                    float t = fmaf(zf[i].x, ef[j].x,
                              fmaf(zf[i].y, ef[j].y,
                              fmaf(zf[i].z, ef[j].z, zf[i].w * ef[j].w)));
                    acc[i][j] += t;
                }
        }

        // ---- epilogue: np-rounded distances + encoding zeros + running argmin ----
        float e2v[8];
        #pragma unroll
        for (int j = 0; j < 8; ++j) e2v[j] = e2_s[kbl + j];
        const int kgbase = kt * 128 + kbl;   // global code base
        #pragma unroll
        for (int i = 0; i < 8; ++i) {
            const int r = mg * 8 + i;
            const float z2 = z2_s[r];
            const size_t nrow = (size_t)(n0 + r) * K_CODES + kgbase;
            float dk[8];
            #pragma unroll
            for (int j = 0; j < 8; ++j) {
                const float t1 = z2 + e2v[j];            // fl(z2 + e2_k) — np's broadcast add
                dk[j] = fmaf(-2.f, acc[i][j], t1);       // fl(t1 - 2*dot) — np's subtract
                // ascending-index scan: strict < keeps lowest index on quantized ties
                if (dk[j] < min1[i]) { min1[i] = dk[j]; idx1[i] = kgbase + j; }
            }
            #pragma unroll
            for (int j = 0; j < 8; j += 2) {
                *(float2*)(dist_out + nrow + j) = make_float2(dk[j], dk[j + 1]);
                *(float2*)(enc_out  + nrow + j) = make_float2(0.f, 0.f);
            }
        }
    }

    // ---- cross-thread argmin reduction (16 candidates per row, lex (v,idx)) ----
    __syncthreads();   // e_s compute reads + z2_s reads finished; safe to alias
    float* m1_s = e_s;                      // [128][16] floats
    int*   i1_s = (int*)(e_s + 2048);       // [128][16] ints
    int*   fidx_s = (int*)z2_s;             // [128] final indices (aliases z2_s)
    {
        const int c = slab * 8 + kg;
        #pragma unroll
        for (int i = 0; i < 8; ++i) {
            const int r = mg * 8 + i;
            m1_s[r * 16 + c] = min1[i];
            i1_s[r * 16 + c] = idx1[i];
        }
    }
    __syncthreads();
    if (tid < BM) {
        float best = m1_s[tid * 16];
        int  bidx  = i1_s[tid * 16];
        #pragma unroll
        for (int c = 1; c < 16; ++c) {
            float v = m1_s[tid * 16 + c];
            int  id = i1_s[tid * 16 + c];
            if (v < best || (v == best && id < bidx)) { best = v; bidx = id; }
        }
        fidx_s[tid] = bidx;
        const int n = n0 + tid;
        out[OFF_IND + n] = (float)bidx;
        enc_out[(size_t)n * K_CODES + bidx] = 1.0f;   // ordered after zero-writes by __syncthreads
        atomicAdd(&hist[bidx], 1u);
    }
    __syncthreads();

    // ---- quantize output (NCHW) + commitment/embedding loss partial ----
    {
        const int w    = tid & 63;
        const int p    = (tid >> 6) & 1;
        const int half = tid >> 7;
        const int r    = p * 64 + w;
        const int n    = n0 + r;
        const int b    = n >> 12;
        const int h    = (n >> 6) & 63;
        const int idx  = fidx_s[r];
        const float* erow = emb + (size_t)idx * DDIM;
        const float* zr   = z_s + r * 68 + (r >> 3) * 4;
        float* qout = out + OFF_Q + (size_t)b * CHW + (size_t)h * 64 + w;
        float lsum = 0.f;
        #pragma unroll
        for (int dd = 0; dd < 32; ++dd) {
            int d = half * 32 + dd;
            float q = erow[d];
            qout[(size_t)d * HW] = q;
            float diff = q - zr[d];
            lsum = fmaf(diff, diff, lsum);
        }
        #pragma unroll
        for (int off = 32; off; off >>= 1) lsum += __shfl_down(lsum, off, 64);
        if ((tid & 63) == 0) red_s[tid >> 6] = lsum;
        __syncthreads();
        if (tid == 0) {
            double tot = (double)red_s[0] + red_s[1] + red_s[2] + red_s[3];
            atomicAdd(ssd, tot);
        }
    }
}

__global__ void vq_final(const unsigned* __restrict__ hist, const double* __restrict__ ssd,
                         float* __restrict__ out) {
    __shared__ double red[4];
    int tid = threadIdx.x;
    double s = 0.0;
    for (int k = tid; k < K_CODES; k += 256) {
        double p = (double)hist[k] / 65536.0;
        s += p * log(p + 1e-10);
    }
    #pragma unroll
    for (int off = 32; off; off >>= 1) s += __shfl_down(s, off, 64);
    if ((tid & 63) == 0) red[tid >> 6] = s;
    __syncthreads();
    if (tid == 0) {
        double t = red[0] + red[1] + red[2] + red[3];
        out[OFF_PERP] = (float)exp(-t);
        out[OFF_LOSS] = (float)(1.25 * (*ssd) / 4194304.0);
    }
}

extern "C" void kernel_launch(void* const* d_in, const int* in_sizes, int n_in,
                              void* d_out, int out_size, void* d_ws, size_t ws_size,
                              hipStream_t stream) {
    const float* lat = (const float*)d_in[0];
    const float* emb = (const float*)d_in[1];
    float* out = (float*)d_out;
    float*    e2w  = (float*)((char*)d_ws + WS_E2);
    unsigned* hist = (unsigned*)((char*)d_ws + WS_HIST);
    double*   ssd  = (double*)((char*)d_ws + WS_SSD);

    vq_init<<<4, 256, 0, stream>>>(emb, e2w, hist, ssd);
    vq_main<<<512, 256, 0, stream>>>(lat, emb, e2w, hist, ssd, out);
    vq_final<<<1, 256, 0, stream>>>(hist, ssd, out);
}